// Round 1
// baseline (1973.358 us; speedup 1.0000x reference)
//
#include <hip/hip_runtime.h>
#include <hip/hip_bf16.h>

// Problem constants (match reference)
#define D_      256
#define NH_     8
#define HD_     32
#define NL_     3
#define NP_4    4
#define BS_     32
#define LQ_     300
#define LV_     8400
#define DFF_    1024
#define NTOK    (BS_ * LQ_)        // 9600
#define NVAL    (BS_ * LV_)        // 268800

// ---------------------------------------------------------------------------
// Elementwise add: o = a + b   (n4 float4 elements)
// ---------------------------------------------------------------------------
__global__ __launch_bounds__(256)
void add_kernel(const float* __restrict__ a, const float* __restrict__ b,
                float* __restrict__ o, int n4) {
    int i = blockIdx.x * 256 + threadIdx.x;
    if (i < n4) {
        float4 x = ((const float4*)a)[i];
        float4 y = ((const float4*)b)[i];
        float4 z; z.x = x.x + y.x; z.y = x.y + y.y; z.z = x.z + y.z; z.w = x.w + y.w;
        ((float4*)o)[i] = z;
    }
}

// ---------------------------------------------------------------------------
// Tiled f32 GEMM: C[M,N] = A[M,K] @ W[K,N] + bias[N]
// MODE 0: f32 out, 1: f32+ReLU out, 2: bf16 out
// BM=BN=64, BK=16, 256 threads, 4x4 microtile
// ---------------------------------------------------------------------------
template <int MODE>
__global__ __launch_bounds__(256)
void gemm_kernel(const float* __restrict__ A, const float* __restrict__ W,
                 const float* __restrict__ bias, void* __restrict__ Cout,
                 int M, int N, int K) {
    __shared__ float As[16][64];
    __shared__ float Ws[16][64];
    const int tid = threadIdx.x;
    const int rowBase = blockIdx.y * 64;
    const int colBase = blockIdx.x * 64;
    const int tRow = tid >> 4;          // 0..15
    const int tCol = tid & 15;          // 0..15
    const int lm = tid >> 2;            // 0..63  A-tile row
    const int lk = (tid & 3) * 4;       // 0,4,8,12
    const int wk = tid >> 4;            // 0..15  W-tile k
    const int wn = (tid & 15) * 4;      // 0..60

    float acc[4][4];
    #pragma unroll
    for (int i = 0; i < 4; ++i)
        #pragma unroll
        for (int j = 0; j < 4; ++j) acc[i][j] = 0.f;

    for (int k0 = 0; k0 < K; k0 += 16) {
        // Load A tile (64x16), store transposed As[k][m]
        {
            int arow = rowBase + lm;
            float4 av = make_float4(0.f, 0.f, 0.f, 0.f);
            if (arow < M) av = *(const float4*)(A + (size_t)arow * K + k0 + lk);
            As[lk + 0][lm] = av.x;
            As[lk + 1][lm] = av.y;
            As[lk + 2][lm] = av.z;
            As[lk + 3][lm] = av.w;
        }
        // Load W tile (16x64)
        {
            int wcol = colBase + wn;
            float4 wv = make_float4(0.f, 0.f, 0.f, 0.f);
            if (wcol < N) wv = *(const float4*)(W + (size_t)(k0 + wk) * N + wcol);
            *(float4*)&Ws[wk][wn] = wv;
        }
        __syncthreads();
        #pragma unroll
        for (int kk = 0; kk < 16; ++kk) {
            float a[4], w[4];
            #pragma unroll
            for (int i = 0; i < 4; ++i) a[i] = As[kk][tRow * 4 + i];
            #pragma unroll
            for (int j = 0; j < 4; ++j) w[j] = Ws[kk][tCol * 4 + j];
            #pragma unroll
            for (int i = 0; i < 4; ++i)
                #pragma unroll
                for (int j = 0; j < 4; ++j) acc[i][j] += a[i] * w[j];
        }
        __syncthreads();
    }

    #pragma unroll
    for (int i = 0; i < 4; ++i) {
        int row = rowBase + tRow * 4 + i;
        if (row >= M) continue;
        #pragma unroll
        for (int j = 0; j < 4; ++j) {
            int col = colBase + tCol * 4 + j;
            if (col >= N) continue;
            float c = acc[i][j] + bias[col];
            if (MODE == 1) c = fmaxf(c, 0.f);
            if (MODE == 2)
                ((__hip_bfloat16*)Cout)[(size_t)row * N + col] = __float2bfloat16(c);
            else
                ((float*)Cout)[(size_t)row * N + col] = c;
        }
    }
}

// ---------------------------------------------------------------------------
// Self-attention: one wave per (b, q, h). 300 keys, scores in LDS.
// out[b,q,h*32+c] = softmax(qh . kh / sqrt(32)) @ vh
// ---------------------------------------------------------------------------
__global__ __launch_bounds__(256)
void attn_kernel(const float* __restrict__ qh, const float* __restrict__ kh,
                 const float* __restrict__ vh, float* __restrict__ out) {
    __shared__ float sc[4][304];
    __shared__ float qv[4][32];
    const int w    = threadIdx.x >> 6;
    const int lane = threadIdx.x & 63;
    const int wid  = blockIdx.x * 4 + w;     // 0 .. 76799
    const int h    = wid & 7;
    const int bq   = wid >> 3;               // b*300 + q
    const int b    = bq / LQ_;

    if (lane < 32) qv[w][lane] = qh[(size_t)bq * D_ + h * HD_ + lane];
    __syncthreads();

    const float scale = 0.17677669529663687f;   // 1/sqrt(32)
    const float* kbase = kh + (size_t)b * LQ_ * D_ + h * HD_;
    for (int k = lane; k < LQ_; k += 64) {
        const float* kp = kbase + (size_t)k * D_;
        float d = 0.f;
        #pragma unroll
        for (int c = 0; c < 32; ++c) d += qv[w][c] * kp[c];
        sc[w][k] = d * scale;
    }
    __syncthreads();

    float m = -1e30f;
    for (int k = lane; k < LQ_; k += 64) m = fmaxf(m, sc[w][k]);
    #pragma unroll
    for (int i = 1; i < 64; i <<= 1) m = fmaxf(m, __shfl_xor(m, i));
    float s = 0.f;
    for (int k = lane; k < LQ_; k += 64) {
        float e = __expf(sc[w][k] - m);
        sc[w][k] = e;
        s += e;
    }
    #pragma unroll
    for (int i = 1; i < 64; i <<= 1) s += __shfl_xor(s, i);
    float inv = 1.0f / s;
    __syncthreads();

    const int half = lane >> 5, c = lane & 31;
    const float* vbase = vh + (size_t)b * LQ_ * D_ + h * HD_ + c;
    float acc = 0.f;
    for (int k = half; k < LQ_; k += 2)
        acc += sc[w][k] * vbase[(size_t)k * D_];
    acc += __shfl_down(acc, 32);
    if (half == 0) out[(size_t)bq * D_ + h * HD_ + c] = acc * inv;
}

// ---------------------------------------------------------------------------
// LayerNorm: out = LN(x + r) * g + b. One block (256 thr) per token.
// ---------------------------------------------------------------------------
__global__ __launch_bounds__(256)
void ln_kernel(const float* __restrict__ x, const float* __restrict__ r,
               const float* __restrict__ g, const float* __restrict__ bta,
               float* __restrict__ out) {
    const int tok = blockIdx.x;
    const int t = threadIdx.x;
    float v = x[(size_t)tok * D_ + t] + r[(size_t)tok * D_ + t];

    float s = v;
    #pragma unroll
    for (int i = 1; i < 64; i <<= 1) s += __shfl_xor(s, i);
    __shared__ float red1[4];
    if ((t & 63) == 0) red1[t >> 6] = s;
    __syncthreads();
    float mean = (red1[0] + red1[1] + red1[2] + red1[3]) * (1.0f / D_);

    float d = v - mean;
    float s2 = d * d;
    #pragma unroll
    for (int i = 1; i < 64; i <<= 1) s2 += __shfl_xor(s2, i);
    __shared__ float red2[4];
    if ((t & 63) == 0) red2[t >> 6] = s2;
    __syncthreads();
    float var = (red2[0] + red2[1] + red2[2] + red2[3]) * (1.0f / D_);

    out[(size_t)tok * D_ + t] = d * rsqrtf(var + 1e-5f) * g[t] + bta[t];
}

// ---------------------------------------------------------------------------
// Deformable sampling. One 32-lane group per (b,q,h); lane = channel c.
// value: bf16 [b, Lv, h*32+c]; off [b,q,192]; awl [b,q,96]; ref [b,q,3,2]
// out[b,q,h*32+c]
// ---------------------------------------------------------------------------
__device__ inline float dsample(const __hip_bfloat16* vbase, int W, int H,
                                int xi, int yi, float wgt) {
    if (xi < 0 || xi >= W || yi < 0 || yi >= H) return 0.f;
    return wgt * __bfloat162float(vbase[(size_t)(yi * W + xi) * D_]);
}

__global__ __launch_bounds__(256)
void deform_kernel(const __hip_bfloat16* __restrict__ value,
                   const float* __restrict__ off,
                   const float* __restrict__ awl,
                   const float* __restrict__ ref,
                   float* __restrict__ out) {
    const int lvl_hw[3]    = {80, 40, 20};
    const int lvl_start[3] = {0, 6400, 8000};
    const int gid = blockIdx.x * 8 + (threadIdx.x >> 5);   // 0..76799
    const int c   = threadIdx.x & 31;
    const int h   = gid & 7;
    const int bq  = gid >> 3;
    const int b   = bq / LQ_;

    // softmax over 12 attention logits (redundant per lane)
    float lg[12];
    const float* ap = awl + (size_t)bq * 96 + h * 12;
    float m = -1e30f;
    #pragma unroll
    for (int j = 0; j < 12; ++j) { lg[j] = ap[j]; m = fmaxf(m, lg[j]); }
    float s = 0.f;
    #pragma unroll
    for (int j = 0; j < 12; ++j) { lg[j] = __expf(lg[j] - m); s += lg[j]; }
    const float inv = 1.0f / s;

    const float* op = off + (size_t)bq * 192 + h * 24;
    const float* rp = ref + (size_t)bq * 6;

    float acc = 0.f;
    #pragma unroll
    for (int l = 0; l < NL_; ++l) {
        const int W = lvl_hw[l], H = lvl_hw[l];
        const float fw = (float)W, fh = (float)H;
        const float rx = rp[l * 2 + 0], ry = rp[l * 2 + 1];
        const __hip_bfloat16* vbase =
            value + ((size_t)b * LV_ + lvl_start[l]) * D_ + h * HD_ + c;
        #pragma unroll
        for (int p = 0; p < NP_4; ++p) {
            float ox = op[(l * 4 + p) * 2 + 0], oy = op[(l * 4 + p) * 2 + 1];
            float x = (rx + ox / fw) * fw - 0.5f;
            float y = (ry + oy / fh) * fh - 0.5f;
            float x0f = floorf(x), y0f = floorf(y);
            float wx = x - x0f, wy = y - y0f;
            int x0 = (int)x0f, y0 = (int)y0f;
            float a = lg[l * 4 + p] * inv;
            acc += dsample(vbase, W, H, x0,     y0,     a * (1.f - wx) * (1.f - wy));
            acc += dsample(vbase, W, H, x0 + 1, y0,     a * wx * (1.f - wy));
            acc += dsample(vbase, W, H, x0,     y0 + 1, a * (1.f - wx) * wy);
            acc += dsample(vbase, W, H, x0 + 1, y0 + 1, a * wx * wy);
        }
    }
    out[(size_t)bq * D_ + h * HD_ + c] = acc;
}

// ---------------------------------------------------------------------------
// Launch
// ---------------------------------------------------------------------------
static inline void launch_gemm(int mode, const float* A, const float* W,
                               const float* bias, void* C, int M, int N, int K,
                               hipStream_t stream) {
    dim3 grid((N + 63) / 64, (M + 63) / 64);
    if (mode == 0)
        gemm_kernel<0><<<grid, 256, 0, stream>>>(A, W, bias, C, M, N, K);
    else if (mode == 1)
        gemm_kernel<1><<<grid, 256, 0, stream>>>(A, W, bias, C, M, N, K);
    else
        gemm_kernel<2><<<grid, 256, 0, stream>>>(A, W, bias, C, M, N, K);
}

extern "C" void kernel_launch(void* const* d_in, const int* in_sizes, int n_in,
                              void* d_out, int out_size, void* d_ws, size_t ws_size,
                              hipStream_t stream) {
    const float* tgt   = (const float*)d_in[0];
    const float* refpt = (const float*)d_in[1];
    const float* mem   = (const float*)d_in[2];
    const float* qpos  = (const float*)d_in[3];
    // d_in[4], d_in[5]: spatial shapes / level starts (hard-coded constants)
    const float* Wq = (const float*)d_in[6],  *bq = (const float*)d_in[7];
    const float* Wk = (const float*)d_in[8],  *bk = (const float*)d_in[9];
    const float* Wv = (const float*)d_in[10], *bv = (const float*)d_in[11];
    const float* Wo = (const float*)d_in[12], *bo = (const float*)d_in[13];
    const float* ln1_g = (const float*)d_in[14], *ln1_b = (const float*)d_in[15];
    const float* W_vproj = (const float*)d_in[16], *b_vproj = (const float*)d_in[17];
    const float* W_off  = (const float*)d_in[18], *b_off  = (const float*)d_in[19];
    const float* W_attn = (const float*)d_in[20], *b_attn = (const float*)d_in[21];
    const float* W_out  = (const float*)d_in[22], *b_out  = (const float*)d_in[23];
    const float* ln2_g = (const float*)d_in[24], *ln2_b = (const float*)d_in[25];
    const float* W1 = (const float*)d_in[26], *b1 = (const float*)d_in[27];
    const float* W2 = (const float*)d_in[28], *b2 = (const float*)d_in[29];
    const float* ln3_g = (const float*)d_in[30], *ln3_b = (const float*)d_in[31];
    float* out = (float*)d_out;

    // workspace layout (floats)
    float* ws = (float*)d_ws;
    const size_t TOKD = (size_t)NTOK * D_;   // 2457600
    float* buf_q    = ws;
    float* buf_qh   = ws + TOKD;
    float* buf_kh   = ws + 2 * TOKD;
    float* buf_vh   = ws + 3 * TOKD;
    float* buf_attn = ws + 4 * TOKD;     // also deform-sampled output
    float* buf_tmp  = ws + 5 * TOKD;
    float* buf_t1   = ws + 6 * TOKD;
    float* buf_t2   = ws + 7 * TOKD;
    float* buf_off  = ws + 8 * TOKD;                        // 9600*192
    float* buf_awl  = buf_off + (size_t)NTOK * 192;         // 9600*96
    float* buf_big  = buf_awl + (size_t)NTOK * 96;          // value bf16 / ffn f32
    __hip_bfloat16* buf_value = (__hip_bfloat16*)buf_big;
    float* buf_ffn  = buf_big;   // aliases value region (value dead by FFN)

    const int n4 = (int)(TOKD / 4);
    const int addGrid = (n4 + 255) / 256;

    // --- self attention ---
    add_kernel<<<addGrid, 256, 0, stream>>>(tgt, qpos, buf_q, n4);
    launch_gemm(0, buf_q, Wq, bq, buf_qh, NTOK, D_, D_, stream);
    launch_gemm(0, buf_q, Wk, bk, buf_kh, NTOK, D_, D_, stream);
    launch_gemm(0, tgt,   Wv, bv, buf_vh, NTOK, D_, D_, stream);
    attn_kernel<<<(BS_ * LQ_ * NH_) / 4, 256, 0, stream>>>(buf_qh, buf_kh, buf_vh, buf_attn);
    launch_gemm(0, buf_attn, Wo, bo, buf_tmp, NTOK, D_, D_, stream);
    ln_kernel<<<NTOK, 256, 0, stream>>>(tgt, buf_tmp, ln1_g, ln1_b, buf_t1);

    // --- deformable cross attention ---
    add_kernel<<<addGrid, 256, 0, stream>>>(buf_t1, qpos, buf_q, n4);
    launch_gemm(2, mem, W_vproj, b_vproj, buf_value, NVAL, D_, D_, stream);
    launch_gemm(0, buf_q, W_off,  b_off,  buf_off, NTOK, 192, D_, stream);
    launch_gemm(0, buf_q, W_attn, b_attn, buf_awl, NTOK, 96,  D_, stream);
    deform_kernel<<<(BS_ * LQ_ * NH_) / 8, 256, 0, stream>>>(buf_value, buf_off, buf_awl, refpt, buf_attn);
    launch_gemm(0, buf_attn, W_out, b_out, buf_tmp, NTOK, D_, D_, stream);
    ln_kernel<<<NTOK, 256, 0, stream>>>(buf_t1, buf_tmp, ln2_g, ln2_b, buf_t2);

    // --- FFN ---
    launch_gemm(1, buf_t2, W1, b1, buf_ffn, NTOK, DFF_, D_, stream);
    launch_gemm(0, buf_ffn, W2, b2, buf_tmp, NTOK, D_, DFF_, stream);
    ln_kernel<<<NTOK, 256, 0, stream>>>(buf_t2, buf_tmp, ln3_g, ln3_b, out);
}

// Round 2
// 927.742 us; speedup vs baseline: 2.1271x; 2.1271x over previous
//
#include <hip/hip_runtime.h>
#include <hip/hip_bf16.h>

// Problem constants
#define D_      256
#define NH_     8
#define HD_     32
#define NL_     3
#define NP_4    4
#define BS_     32
#define LQ_     300
#define LV_     8400
#define DFF_    1024
#define NTOK    (BS_ * LQ_)        // 9600
#define NVAL    (BS_ * LV_)        // 268800

typedef __attribute__((ext_vector_type(8))) short bf16x8;
typedef __attribute__((ext_vector_type(4))) float f32x4;

__device__ inline unsigned short f2bf(float x) {
    union { float f; unsigned u; } v; v.f = x;
    unsigned r = v.u + 0x7FFFu + ((v.u >> 16) & 1u);
    return (unsigned short)(r >> 16);
}
__device__ inline float bf2f(unsigned short x) {
    union { unsigned u; float f; } v; v.u = ((unsigned)x) << 16;
    return v.f;
}

// ---------------------------------------------------------------------------
// Weight transpose+convert: Wt[n][k] = bf16(W[k][n]). 10 weights in one launch.
// ---------------------------------------------------------------------------
struct TrDesc { const float* W; unsigned short* Wt; int K; int N; };
struct TrPack { TrDesc d[10]; };

__global__ __launch_bounds__(256)
void tr_kernel(TrPack p) {
    TrDesc d = p.d[blockIdx.z];
    const int n0 = blockIdx.x * 32, k0 = blockIdx.y * 32;
    if (n0 >= d.N || k0 >= d.K) return;
    __shared__ float t[32][33];
    const int tx = threadIdx.x & 31, ty = threadIdx.x >> 5;   // ty 0..7
    #pragma unroll
    for (int i = 0; i < 4; ++i) {
        int k = k0 + ty + i * 8, n = n0 + tx;
        t[ty + i * 8][tx] = (k < d.K && n < d.N) ? d.W[(size_t)k * d.N + n] : 0.f;
    }
    __syncthreads();
    #pragma unroll
    for (int i = 0; i < 4; ++i) {
        int n = n0 + ty + i * 8, k = k0 + tx;
        if (n < d.N && k < d.K) d.Wt[(size_t)n * d.K + k] = f2bf(t[tx][ty + i * 8]);
    }
}

// ---------------------------------------------------------------------------
// Elementwise add
// ---------------------------------------------------------------------------
__global__ __launch_bounds__(256)
void add_kernel(const float* __restrict__ a, const float* __restrict__ b,
                float* __restrict__ o, int n4) {
    int i = blockIdx.x * 256 + threadIdx.x;
    if (i < n4) {
        float4 x = ((const float4*)a)[i];
        float4 y = ((const float4*)b)[i];
        float4 z; z.x = x.x + y.x; z.y = x.y + y.y; z.z = x.z + y.z; z.w = x.w + y.w;
        ((float4*)o)[i] = z;
    }
}

// ---------------------------------------------------------------------------
// bf16 MFMA GEMM: C[M,N] = A[M,K](f32) @ W[K,N] + bias. Wt is [N][K] bf16.
// 128x128 tile, BK=32, 4 waves in 2x2, each wave 4x4 16x16 tiles.
// M must be a multiple of 128; K a multiple of 32.
// MODE 0: f32 out, 1: f32 ReLU, 2: bf16 out
// ---------------------------------------------------------------------------
template <int MODE>
__global__ __launch_bounds__(256)
void gemm_mfma(const float* __restrict__ A, const unsigned short* __restrict__ Wt,
               const float* __restrict__ bias, void* __restrict__ Cout,
               int M, int N, int K) {
    __shared__ unsigned short As[128 * 40];   // stride 40 bf16 = 80 B (16B-aligned rows)
    __shared__ unsigned short Bs[128 * 40];
    const int tid = threadIdx.x;
    const int lane = tid & 63, w = tid >> 6;
    const int quad = lane >> 4, l16 = lane & 15;
    const int wr = w >> 1, wc = w & 1;
    const int rowBase = blockIdx.y * 128, colBase = blockIdx.x * 128;

    f32x4 acc[4][4];
    #pragma unroll
    for (int i = 0; i < 4; ++i)
        #pragma unroll
        for (int j = 0; j < 4; ++j)
            #pragma unroll
            for (int r = 0; r < 4; ++r) acc[i][j][r] = 0.f;

    for (int k0 = 0; k0 < K; k0 += 32) {
        #pragma unroll
        for (int i = 0; i < 4; ++i) {           // A tile: 128x32 f32 -> bf16
            int c = tid + 256 * i;
            int row = c >> 3, kq = (c & 7) * 4;
            float4 av = *(const float4*)(A + (size_t)(rowBase + row) * K + k0 + kq);
            ushort4 sv;
            sv.x = f2bf(av.x); sv.y = f2bf(av.y); sv.z = f2bf(av.z); sv.w = f2bf(av.w);
            *(ushort4*)&As[row * 40 + kq] = sv;
        }
        #pragma unroll
        for (int i = 0; i < 4; ++i) {           // B tile: 128 n-rows x 32 k
            int c = tid + 256 * i;
            int row = c >> 3, kq = (c & 7) * 4;
            ushort4 bv = make_ushort4(0, 0, 0, 0);
            if (colBase + row < N)
                bv = *(const ushort4*)(Wt + (size_t)(colBase + row) * K + k0 + kq);
            *(ushort4*)&Bs[row * 40 + kq] = bv;
        }
        __syncthreads();
        bf16x8 af[4], bfr[4];
        #pragma unroll
        for (int i = 0; i < 4; ++i)
            af[i] = *(const bf16x8*)&As[(wr * 64 + i * 16 + l16) * 40 + quad * 8];
        #pragma unroll
        for (int j = 0; j < 4; ++j)
            bfr[j] = *(const bf16x8*)&Bs[(wc * 64 + j * 16 + l16) * 40 + quad * 8];
        #pragma unroll
        for (int i = 0; i < 4; ++i)
            #pragma unroll
            for (int j = 0; j < 4; ++j)
                acc[i][j] = __builtin_amdgcn_mfma_f32_16x16x32_bf16(af[i], bfr[j], acc[i][j], 0, 0, 0);
        __syncthreads();
    }

    #pragma unroll
    for (int i = 0; i < 4; ++i) {
        #pragma unroll
        for (int j = 0; j < 4; ++j) {
            int col = colBase + wc * 64 + j * 16 + l16;
            if (col >= N) continue;
            float bb = bias[col];
            #pragma unroll
            for (int r = 0; r < 4; ++r) {
                int row = rowBase + wr * 64 + i * 16 + quad * 4 + r;
                float c = acc[i][j][r] + bb;
                if (MODE == 1) c = fmaxf(c, 0.f);
                if (MODE == 2)
                    ((unsigned short*)Cout)[(size_t)row * N + col] = f2bf(c);
                else
                    ((float*)Cout)[(size_t)row * N + col] = c;
            }
        }
    }
}

// ---------------------------------------------------------------------------
// Flash-style MFMA self-attention. Block = (b,h), 4 waves; wave owns 16-query
// tiles. Q,K,V bf16 [b, q, h*32+c]. Scores for all 300 (pad 304) keys kept in
// registers; P -> LDS (A-layout) -> PV MFMA. Output f32.
// ---------------------------------------------------------------------------
#define PS_STRIDE 344
__global__ __launch_bounds__(256)
void attn_mfma(const unsigned short* __restrict__ qh,
               const unsigned short* __restrict__ kh,
               const unsigned short* __restrict__ vh,
               float* __restrict__ out) {
    __shared__ unsigned short Ps[4 * 16 * PS_STRIDE];   // 44032 B, per-wave 16x(320)
    __shared__ unsigned short Vs[32 * PS_STRIDE];       // 22016 B, V^T [c][key]
    const int tid = threadIdx.x;
    const int b = blockIdx.x >> 3, h = blockIdx.x & 7;
    const int w = tid >> 6, lane = tid & 63;
    const int quad = lane >> 4, l16 = lane & 15;

    // zero Ps (keys 304..319 must be 0 for the PV tail)
    for (int i = tid; i < 4 * 16 * PS_STRIDE / 2; i += 256) ((unsigned*)Ps)[i] = 0u;

    const size_t hbase = ((size_t)b * LQ_) * D_ + h * HD_;
    // stage V transposed; zero keys 300..319
    for (int it = 0; it < 10; ++it) {
        int chunk = tid + 256 * it;          // 0..2559
        int key = chunk >> 3, cc = (chunk & 7) * 4;
        ushort4 v = make_ushort4(0, 0, 0, 0);
        if (key < LQ_) v = *(const ushort4*)(vh + hbase + (size_t)key * D_ + cc);
        Vs[(cc + 0) * PS_STRIDE + key] = v.x;
        Vs[(cc + 1) * PS_STRIDE + key] = v.y;
        Vs[(cc + 2) * PS_STRIDE + key] = v.z;
        Vs[(cc + 3) * PS_STRIDE + key] = v.w;
    }
    __syncthreads();

    const unsigned short* qb = qh + hbase;
    const unsigned short* kb = kh + hbase;
    const float scale = 0.17677669529663687f;   // 1/sqrt(32)

    for (int qt = w; qt < 19; qt += 4) {
        int rowq = qt * 16 + l16; if (rowq > LQ_ - 1) rowq = LQ_ - 1;
        bf16x8 aq = *(const bf16x8*)(qb + (size_t)rowq * D_ + quad * 8);

        f32x4 S[19];
        #pragma unroll
        for (int kt = 0; kt < 19; ++kt) {
            int rowk = kt * 16 + l16; if (rowk > LQ_ - 1) rowk = LQ_ - 1;
            bf16x8 bk = *(const bf16x8*)(kb + (size_t)rowk * D_ + quad * 8);
            f32x4 z; z[0] = z[1] = z[2] = z[3] = 0.f;
            S[kt] = __builtin_amdgcn_mfma_f32_16x16x32_bf16(aq, bk, z, 0, 0, 0);
        }
        float mrow[4] = {-1e30f, -1e30f, -1e30f, -1e30f};
        #pragma unroll
        for (int kt = 0; kt < 19; ++kt) {
            bool masked = (kt == 18) && (l16 >= 12);    // keys 300..303
            #pragma unroll
            for (int r = 0; r < 4; ++r) {
                float s = masked ? -1e30f : S[kt][r] * scale;
                S[kt][r] = s;
                mrow[r] = fmaxf(mrow[r], s);
            }
        }
        #pragma unroll
        for (int r = 0; r < 4; ++r)
            #pragma unroll
            for (int off = 1; off < 16; off <<= 1)
                mrow[r] = fmaxf(mrow[r], __shfl_xor(mrow[r], off));
        float psum[4] = {0.f, 0.f, 0.f, 0.f};
        #pragma unroll
        for (int kt = 0; kt < 19; ++kt)
            #pragma unroll
            for (int r = 0; r < 4; ++r) {
                float p = __expf(S[kt][r] - mrow[r]);
                S[kt][r] = p;
                psum[r] += p;
            }
        #pragma unroll
        for (int r = 0; r < 4; ++r)
            #pragma unroll
            for (int off = 1; off < 16; off <<= 1)
                psum[r] += __shfl_xor(psum[r], off);
        float linv[4];
        #pragma unroll
        for (int r = 0; r < 4; ++r) linv[r] = 1.f / psum[r];

        unsigned short* pw = Ps + w * (16 * PS_STRIDE);
        #pragma unroll
        for (int kt = 0; kt < 19; ++kt)
            #pragma unroll
            for (int r = 0; r < 4; ++r)
                pw[(quad * 4 + r) * PS_STRIDE + kt * 16 + l16] = f2bf(S[kt][r]);

        f32x4 o0, o1;
        #pragma unroll
        for (int r = 0; r < 4; ++r) { o0[r] = 0.f; o1[r] = 0.f; }
        #pragma unroll
        for (int ks = 0; ks < 10; ++ks) {
            bf16x8 ap = *(const bf16x8*)(pw + l16 * PS_STRIDE + ks * 32 + quad * 8);
            bf16x8 b0 = *(const bf16x8*)(Vs + l16 * PS_STRIDE + ks * 32 + quad * 8);
            bf16x8 b1 = *(const bf16x8*)(Vs + (16 + l16) * PS_STRIDE + ks * 32 + quad * 8);
            o0 = __builtin_amdgcn_mfma_f32_16x16x32_bf16(ap, b0, o0, 0, 0, 0);
            o1 = __builtin_amdgcn_mfma_f32_16x16x32_bf16(ap, b1, o1, 0, 0, 0);
        }
        #pragma unroll
        for (int r = 0; r < 4; ++r) {
            int q = qt * 16 + quad * 4 + r;
            if (q < LQ_) {
                size_t ob = ((size_t)b * LQ_ + q) * D_ + h * HD_;
                out[ob + l16]      = o0[r] * linv[r];
                out[ob + 16 + l16] = o1[r] * linv[r];
            }
        }
    }
}

// ---------------------------------------------------------------------------
// LayerNorm: out = LN(x + r) * g + b. One block per token.
// ---------------------------------------------------------------------------
__global__ __launch_bounds__(256)
void ln_kernel(const float* __restrict__ x, const float* __restrict__ r,
               const float* __restrict__ g, const float* __restrict__ bta,
               float* __restrict__ out) {
    const int tok = blockIdx.x;
    const int t = threadIdx.x;
    float v = x[(size_t)tok * D_ + t] + r[(size_t)tok * D_ + t];

    float s = v;
    #pragma unroll
    for (int i = 1; i < 64; i <<= 1) s += __shfl_xor(s, i);
    __shared__ float red1[4];
    if ((t & 63) == 0) red1[t >> 6] = s;
    __syncthreads();
    float mean = (red1[0] + red1[1] + red1[2] + red1[3]) * (1.0f / D_);

    float d = v - mean;
    float s2 = d * d;
    #pragma unroll
    for (int i = 1; i < 64; i <<= 1) s2 += __shfl_xor(s2, i);
    __shared__ float red2[4];
    if ((t & 63) == 0) red2[t >> 6] = s2;
    __syncthreads();
    float var = (red2[0] + red2[1] + red2[2] + red2[3]) * (1.0f / D_);

    out[(size_t)tok * D_ + t] = d * rsqrtf(var + 1e-5f) * g[t] + bta[t];
}

// ---------------------------------------------------------------------------
// Deformable sampling (unchanged structure, value bf16-as-ushort)
// ---------------------------------------------------------------------------
__device__ inline float dsample(const unsigned short* vbase, int W, int H,
                                int xi, int yi, float wgt) {
    if (xi < 0 || xi >= W || yi < 0 || yi >= H) return 0.f;
    return wgt * bf2f(vbase[(size_t)(yi * W + xi) * D_]);
}

__global__ __launch_bounds__(256)
void deform_kernel(const unsigned short* __restrict__ value,
                   const float* __restrict__ off,
                   const float* __restrict__ awl,
                   const float* __restrict__ ref,
                   float* __restrict__ out) {
    const int lvl_hw[3]    = {80, 40, 20};
    const int lvl_start[3] = {0, 6400, 8000};
    const int gid = blockIdx.x * 8 + (threadIdx.x >> 5);
    const int c   = threadIdx.x & 31;
    const int h   = gid & 7;
    const int bq  = gid >> 3;
    const int b   = bq / LQ_;

    float lg[12];
    const float* ap = awl + (size_t)bq * 96 + h * 12;
    float m = -1e30f;
    #pragma unroll
    for (int j = 0; j < 12; ++j) { lg[j] = ap[j]; m = fmaxf(m, lg[j]); }
    float s = 0.f;
    #pragma unroll
    for (int j = 0; j < 12; ++j) { lg[j] = __expf(lg[j] - m); s += lg[j]; }
    const float inv = 1.0f / s;

    const float* op = off + (size_t)bq * 192 + h * 24;
    const float* rp = ref + (size_t)bq * 6;

    float acc = 0.f;
    #pragma unroll
    for (int l = 0; l < NL_; ++l) {
        const int W = lvl_hw[l], H = lvl_hw[l];
        const float fw = (float)W, fh = (float)H;
        const float rx = rp[l * 2 + 0], ry = rp[l * 2 + 1];
        const unsigned short* vbase =
            value + ((size_t)b * LV_ + lvl_start[l]) * D_ + h * HD_ + c;
        #pragma unroll
        for (int p = 0; p < NP_4; ++p) {
            float ox = op[(l * 4 + p) * 2 + 0], oy = op[(l * 4 + p) * 2 + 1];
            float x = (rx + ox / fw) * fw - 0.5f;
            float y = (ry + oy / fh) * fh - 0.5f;
            float x0f = floorf(x), y0f = floorf(y);
            float wx = x - x0f, wy = y - y0f;
            int x0 = (int)x0f, y0 = (int)y0f;
            float a = lg[l * 4 + p] * inv;
            acc += dsample(vbase, W, H, x0,     y0,     a * (1.f - wx) * (1.f - wy));
            acc += dsample(vbase, W, H, x0 + 1, y0,     a * wx * (1.f - wy));
            acc += dsample(vbase, W, H, x0,     y0 + 1, a * (1.f - wx) * wy);
            acc += dsample(vbase, W, H, x0 + 1, y0 + 1, a * wx * wy);
        }
    }
    out[(size_t)bq * D_ + h * HD_ + c] = acc;
}

// ---------------------------------------------------------------------------
// Launch
// ---------------------------------------------------------------------------
static inline void launch_gemm(int mode, const float* A, const unsigned short* Wt,
                               const float* bias, void* C, int M, int N, int K,
                               hipStream_t stream) {
    dim3 grid((N + 127) / 128, M / 128);
    if (mode == 0)
        gemm_mfma<0><<<grid, 256, 0, stream>>>(A, Wt, bias, C, M, N, K);
    else if (mode == 1)
        gemm_mfma<1><<<grid, 256, 0, stream>>>(A, Wt, bias, C, M, N, K);
    else
        gemm_mfma<2><<<grid, 256, 0, stream>>>(A, Wt, bias, C, M, N, K);
}

extern "C" void kernel_launch(void* const* d_in, const int* in_sizes, int n_in,
                              void* d_out, int out_size, void* d_ws, size_t ws_size,
                              hipStream_t stream) {
    const float* tgt   = (const float*)d_in[0];
    const float* refpt = (const float*)d_in[1];
    const float* mem   = (const float*)d_in[2];
    const float* qpos  = (const float*)d_in[3];
    const float* Wq = (const float*)d_in[6],  *bq = (const float*)d_in[7];
    const float* Wk = (const float*)d_in[8],  *bk = (const float*)d_in[9];
    const float* Wv = (const float*)d_in[10], *bv = (const float*)d_in[11];
    const float* Wo = (const float*)d_in[12], *bo = (const float*)d_in[13];
    const float* ln1_g = (const float*)d_in[14], *ln1_b = (const float*)d_in[15];
    const float* W_vproj = (const float*)d_in[16], *b_vproj = (const float*)d_in[17];
    const float* W_off  = (const float*)d_in[18], *b_off  = (const float*)d_in[19];
    const float* W_attn = (const float*)d_in[20], *b_attn = (const float*)d_in[21];
    const float* W_out  = (const float*)d_in[22], *b_out  = (const float*)d_in[23];
    const float* ln2_g = (const float*)d_in[24], *ln2_b = (const float*)d_in[25];
    const float* W1 = (const float*)d_in[26], *b1 = (const float*)d_in[27];
    const float* W2 = (const float*)d_in[28], *b2 = (const float*)d_in[29];
    const float* ln3_g = (const float*)d_in[30], *ln3_b = (const float*)d_in[31];
    float* out = (float*)d_out;

    // ---- workspace layout (bytes) ----
    char* p = (char*)d_ws;
    const size_t TOKD = (size_t)NTOK * D_;
    float* buf_q    = (float*)p; p += TOKD * 4;
    float* buf_attn = (float*)p; p += TOKD * 4;
    float* buf_tmp  = (float*)p; p += TOKD * 4;
    float* buf_t1   = (float*)p; p += TOKD * 4;
    float* buf_t2   = (float*)p; p += TOKD * 4;
    unsigned short* buf_qh = (unsigned short*)p; p += TOKD * 2;
    unsigned short* buf_kh = (unsigned short*)p; p += TOKD * 2;
    unsigned short* buf_vh = (unsigned short*)p; p += TOKD * 2;
    float* buf_off  = (float*)p; p += (size_t)NTOK * 192 * 4;
    float* buf_awl  = (float*)p; p += (size_t)NTOK * 96 * 4;
    unsigned short* wt_q   = (unsigned short*)p; p += 65536 * 2;
    unsigned short* wt_k   = (unsigned short*)p; p += 65536 * 2;
    unsigned short* wt_v   = (unsigned short*)p; p += 65536 * 2;
    unsigned short* wt_o   = (unsigned short*)p; p += 65536 * 2;
    unsigned short* wt_vp  = (unsigned short*)p; p += 65536 * 2;
    unsigned short* wt_off = (unsigned short*)p; p += 49152 * 2;
    unsigned short* wt_awl = (unsigned short*)p; p += 24576 * 2;
    unsigned short* wt_out = (unsigned short*)p; p += 65536 * 2;
    unsigned short* wt_1   = (unsigned short*)p; p += (size_t)262144 * 2;
    unsigned short* wt_2   = (unsigned short*)p; p += (size_t)262144 * 2;
    unsigned short* buf_value = (unsigned short*)p;      // NVAL*256 bf16 = 137.6 MB
    float* buf_ffn = (float*)p;                          // aliases value (dead by FFN)

    // ---- weight transposes (one launch) ----
    TrPack pk;
    pk.d[0] = {Wq,      wt_q,   256, 256};
    pk.d[1] = {Wk,      wt_k,   256, 256};
    pk.d[2] = {Wv,      wt_v,   256, 256};
    pk.d[3] = {Wo,      wt_o,   256, 256};
    pk.d[4] = {W_vproj, wt_vp,  256, 256};
    pk.d[5] = {W_off,   wt_off, 256, 192};
    pk.d[6] = {W_attn,  wt_awl, 256, 96};
    pk.d[7] = {W_out,   wt_out, 256, 256};
    pk.d[8] = {W1,      wt_1,   256, 1024};
    pk.d[9] = {W2,      wt_2,   1024, 256};
    tr_kernel<<<dim3(32, 32, 10), 256, 0, stream>>>(pk);

    const int n4 = (int)(TOKD / 4);
    const int addGrid = (n4 + 255) / 256;

    // --- self attention ---
    add_kernel<<<addGrid, 256, 0, stream>>>(tgt, qpos, buf_q, n4);
    launch_gemm(2, buf_q, wt_q, bq, buf_qh, NTOK, 256, 256, stream);
    launch_gemm(2, buf_q, wt_k, bk, buf_kh, NTOK, 256, 256, stream);
    launch_gemm(2, tgt,   wt_v, bv, buf_vh, NTOK, 256, 256, stream);
    attn_mfma<<<BS_ * NH_, 256, 0, stream>>>(buf_qh, buf_kh, buf_vh, buf_attn);
    launch_gemm(0, buf_attn, wt_o, bo, buf_tmp, NTOK, 256, 256, stream);
    ln_kernel<<<NTOK, 256, 0, stream>>>(tgt, buf_tmp, ln1_g, ln1_b, buf_t1);

    // --- deformable cross attention ---
    add_kernel<<<addGrid, 256, 0, stream>>>(buf_t1, qpos, buf_q, n4);
    launch_gemm(2, mem, wt_vp, b_vproj, buf_value, NVAL, 256, 256, stream);
    launch_gemm(0, buf_q, wt_off, b_off, buf_off, NTOK, 192, 256, stream);
    launch_gemm(0, buf_q, wt_awl, b_attn, buf_awl, NTOK, 96, 256, stream);
    deform_kernel<<<(BS_ * LQ_ * NH_) / 8, 256, 0, stream>>>(buf_value, buf_off, buf_awl, refpt, buf_attn);
    launch_gemm(0, buf_attn, wt_out, b_out, buf_tmp, NTOK, 256, 256, stream);
    ln_kernel<<<NTOK, 256, 0, stream>>>(buf_t1, buf_tmp, ln2_g, ln2_b, buf_t2);

    // --- FFN ---
    launch_gemm(1, buf_t2, wt_1, b1, buf_ffn, NTOK, DFF_, 256, stream);
    launch_gemm(0, buf_ffn, wt_2, b2, buf_tmp, NTOK, 256, DFF_, stream);
    ln_kernel<<<NTOK, 256, 0, stream>>>(buf_t2, buf_tmp, ln3_g, ln3_b, out);
}

// Round 3
// 833.443 us; speedup vs baseline: 2.3677x; 1.1131x over previous
//
#include <hip/hip_runtime.h>
#include <hip/hip_bf16.h>

// Problem constants
#define D_      256
#define NH_     8
#define HD_     32
#define NL_     3
#define NP_4    4
#define BS_     32
#define LQ_     300
#define LV_     8400
#define DFF_    1024
#define NTOK    (BS_ * LQ_)        // 9600
#define NVAL    (BS_ * LV_)        // 268800

typedef __attribute__((ext_vector_type(8))) short bf16x8;
typedef __attribute__((ext_vector_type(4))) float f32x4;

__device__ inline unsigned short f2bf(float x) {
    union { float f; unsigned u; } v; v.f = x;
    unsigned r = v.u + 0x7FFFu + ((v.u >> 16) & 1u);
    return (unsigned short)(r >> 16);
}
__device__ inline float bf2f(unsigned short x) {
    union { unsigned u; float f; } v; v.u = ((unsigned)x) << 16;
    return v.f;
}

// ---------------------------------------------------------------------------
// Weight transpose+convert: Wt[n][k] = bf16(W[k][n]). 10 weights, one launch.
// ---------------------------------------------------------------------------
struct TrDesc { const float* W; unsigned short* Wt; int K; int N; };
struct TrPack { TrDesc d[10]; };

__global__ __launch_bounds__(256)
void tr_kernel(TrPack p) {
    TrDesc d = p.d[blockIdx.z];
    const int n0 = blockIdx.x * 32, k0 = blockIdx.y * 32;
    if (n0 >= d.N || k0 >= d.K) return;
    __shared__ float t[32][33];
    const int tx = threadIdx.x & 31, ty = threadIdx.x >> 5;
    #pragma unroll
    for (int i = 0; i < 4; ++i) {
        int k = k0 + ty + i * 8, n = n0 + tx;
        t[ty + i * 8][tx] = (k < d.K && n < d.N) ? d.W[(size_t)k * d.N + n] : 0.f;
    }
    __syncthreads();
    #pragma unroll
    for (int i = 0; i < 4; ++i) {
        int n = n0 + ty + i * 8, k = k0 + tx;
        if (n < d.N && k < d.K) d.Wt[(size_t)n * d.K + k] = f2bf(t[tx][ty + i * 8]);
    }
}

// ---------------------------------------------------------------------------
// Register-resident-W GEMM. C[M,N] = A[M,K] @ W + bias, Wt = [N][K] bf16.
// Block: 256 thr = 4 waves; wave holds W frags for TC*16 cols in 128 VGPRs,
// computes AROWS x (TC*16). A staged once to LDS (padded), ONE barrier total.
// AMODE: 0 = f32 A, 1 = f32 A + f32 A2 (fused add), 2 = bf16 A.
// CMODE: 0 = f32, 1 = f32 relu, 2 = bf16, 3 = bf16 relu.
// ---------------------------------------------------------------------------
template <int AROWS, int KK, int TC, int AMODE, int CMODE>
__global__ __launch_bounds__(256, 2)
void gemm_wreg(const void* __restrict__ Ain, const float* __restrict__ A2,
               const unsigned short* __restrict__ Wt, const float* __restrict__ bias,
               void* __restrict__ Cout, int M, int N) {
    constexpr int KSTEPS = KK / 32;
    constexpr int RT = AROWS / 16;
    constexpr int LDK = KK + 8;            // pad: row stride 528/2064 B, 2-way banks
    constexpr int TPR = 256 / AROWS;       // threads per A row
    constexpr int KSEG = KK / TPR;         // k elems per staging thread
    __shared__ unsigned short Alds[AROWS * LDK];

    const int tid = threadIdx.x;
    const int lane = tid & 63, w = tid >> 6;
    const int quad = lane >> 4, l16 = lane & 15;
    const int rowBase = blockIdx.y * AROWS;
    const int colW = blockIdx.x * (4 * TC * 16) + w * (TC * 16);

    // ---- W fragments -> registers (one-time, from L2-hot Wt) ----
    bf16x8 wf[TC][KSTEPS];
    #pragma unroll
    for (int j = 0; j < TC; ++j) {
        int col = colW + j * 16 + l16;
        if (col > N - 1) col = N - 1;                  // clamp (stores guarded)
        const unsigned short* wp = Wt + (size_t)col * KK;
        #pragma unroll
        for (int s = 0; s < KSTEPS; ++s)
            wf[j][s] = *(const bf16x8*)(wp + s * 32 + quad * 8);
    }

    // ---- stage A chunk: loads first (in flight), then convert + ds_write ----
    {
        const int row = tid / TPR;
        const int ks = (tid % TPR) * KSEG;
        const size_t gbase = (size_t)(rowBase + row) * KK + ks;
        unsigned short* dst = &Alds[row * LDK + ks];
        if (AMODE == 2) {
            const int4* ap = (const int4*)((const unsigned short*)Ain + gbase);
            int4 wa[KSEG / 8];
            #pragma unroll
            for (int j = 0; j < KSEG / 8; ++j) wa[j] = ap[j];
            #pragma unroll
            for (int j = 0; j < KSEG / 8; ++j) *(int4*)(dst + j * 8) = wa[j];
        } else {
            const float4* ap = (const float4*)((const float*)Ain + gbase);
            float4 va[KSEG / 4];
            #pragma unroll
            for (int j = 0; j < KSEG / 4; ++j) va[j] = ap[j];
            if (AMODE == 1) {
                const float4* bp = (const float4*)(A2 + gbase);
                float4 vb[KSEG / 4];
                #pragma unroll
                for (int j = 0; j < KSEG / 4; ++j) vb[j] = bp[j];
                #pragma unroll
                for (int j = 0; j < KSEG / 4; ++j) {
                    va[j].x += vb[j].x; va[j].y += vb[j].y;
                    va[j].z += vb[j].z; va[j].w += vb[j].w;
                }
            }
            #pragma unroll
            for (int j = 0; j < KSEG / 4; ++j) {
                ushort4 s4;
                s4.x = f2bf(va[j].x); s4.y = f2bf(va[j].y);
                s4.z = f2bf(va[j].z); s4.w = f2bf(va[j].w);
                *(ushort4*)(dst + j * 4) = s4;
            }
        }
    }
    __syncthreads();

    // ---- barrier-free MFMA loop ----
    f32x4 acc[RT][TC];
    #pragma unroll
    for (int rt = 0; rt < RT; ++rt)
        #pragma unroll
        for (int j = 0; j < TC; ++j)
            #pragma unroll
            for (int r = 0; r < 4; ++r) acc[rt][j][r] = 0.f;

    #pragma unroll
    for (int s = 0; s < KSTEPS; ++s) {
        bf16x8 af[RT];
        #pragma unroll
        for (int rt = 0; rt < RT; ++rt)
            af[rt] = *(const bf16x8*)&Alds[(rt * 16 + l16) * LDK + s * 32 + quad * 8];
        #pragma unroll
        for (int rt = 0; rt < RT; ++rt)
            #pragma unroll
            for (int j = 0; j < TC; ++j)
                acc[rt][j] = __builtin_amdgcn_mfma_f32_16x16x32_bf16(af[rt], wf[j][s], acc[rt][j], 0, 0, 0);
    }

    // ---- epilogue ----
    #pragma unroll
    for (int rt = 0; rt < RT; ++rt) {
        #pragma unroll
        for (int j = 0; j < TC; ++j) {
            int col = colW + j * 16 + l16;
            if (col >= N) continue;
            float bb = bias[col];
            #pragma unroll
            for (int r = 0; r < 4; ++r) {
                int row = rowBase + rt * 16 + quad * 4 + r;
                float c = acc[rt][j][r] + bb;
                if (CMODE == 1 || CMODE == 3) c = fmaxf(c, 0.f);
                if (CMODE >= 2)
                    ((unsigned short*)Cout)[(size_t)row * N + col] = f2bf(c);
                else
                    ((float*)Cout)[(size_t)row * N + col] = c;
            }
        }
    }
}

// ---------------------------------------------------------------------------
// Flash-style MFMA self-attention. Block = (b, h, half); 512 blocks.
// ---------------------------------------------------------------------------
#define PS_STRIDE 344
__global__ __launch_bounds__(256)
void attn_mfma(const unsigned short* __restrict__ qh,
               const unsigned short* __restrict__ kh,
               const unsigned short* __restrict__ vh,
               float* __restrict__ out) {
    __shared__ unsigned short Ps[4 * 16 * PS_STRIDE];
    __shared__ unsigned short Vs[32 * PS_STRIDE];
    const int tid = threadIdx.x;
    const int bh = blockIdx.x >> 1, half_ = blockIdx.x & 1;
    const int b = bh >> 3, h = bh & 7;
    const int w = tid >> 6, lane = tid & 63;
    const int quad = lane >> 4, l16 = lane & 15;

    for (int i = tid; i < 4 * 16 * PS_STRIDE / 2; i += 256) ((unsigned*)Ps)[i] = 0u;

    const size_t hbase = ((size_t)b * LQ_) * D_ + h * HD_;
    for (int it = 0; it < 10; ++it) {
        int chunk = tid + 256 * it;
        int key = chunk >> 3, cc = (chunk & 7) * 4;
        ushort4 v = make_ushort4(0, 0, 0, 0);
        if (key < LQ_) v = *(const ushort4*)(vh + hbase + (size_t)key * D_ + cc);
        Vs[(cc + 0) * PS_STRIDE + key] = v.x;
        Vs[(cc + 1) * PS_STRIDE + key] = v.y;
        Vs[(cc + 2) * PS_STRIDE + key] = v.z;
        Vs[(cc + 3) * PS_STRIDE + key] = v.w;
    }
    __syncthreads();

    const unsigned short* qb = qh + hbase;
    const unsigned short* kb = kh + hbase;
    const float scale = 0.17677669529663687f;

    for (int qt = 10 * half_ + w; qt < 10 * half_ + 10 && qt < 19; qt += 4) {
        int rowq = qt * 16 + l16; if (rowq > LQ_ - 1) rowq = LQ_ - 1;
        bf16x8 aq = *(const bf16x8*)(qb + (size_t)rowq * D_ + quad * 8);

        f32x4 S[19];
        #pragma unroll
        for (int kt = 0; kt < 19; ++kt) {
            int rowk = kt * 16 + l16; if (rowk > LQ_ - 1) rowk = LQ_ - 1;
            bf16x8 bk = *(const bf16x8*)(kb + (size_t)rowk * D_ + quad * 8);
            f32x4 z; z[0] = z[1] = z[2] = z[3] = 0.f;
            S[kt] = __builtin_amdgcn_mfma_f32_16x16x32_bf16(aq, bk, z, 0, 0, 0);
        }
        float mrow[4] = {-1e30f, -1e30f, -1e30f, -1e30f};
        #pragma unroll
        for (int kt = 0; kt < 19; ++kt) {
            bool masked = (kt == 18) && (l16 >= 12);
            #pragma unroll
            for (int r = 0; r < 4; ++r) {
                float s = masked ? -1e30f : S[kt][r] * scale;
                S[kt][r] = s;
                mrow[r] = fmaxf(mrow[r], s);
            }
        }
        #pragma unroll
        for (int r = 0; r < 4; ++r)
            #pragma unroll
            for (int off = 1; off < 16; off <<= 1)
                mrow[r] = fmaxf(mrow[r], __shfl_xor(mrow[r], off));
        float psum[4] = {0.f, 0.f, 0.f, 0.f};
        #pragma unroll
        for (int kt = 0; kt < 19; ++kt)
            #pragma unroll
            for (int r = 0; r < 4; ++r) {
                float p = __expf(S[kt][r] - mrow[r]);
                S[kt][r] = p;
                psum[r] += p;
            }
        #pragma unroll
        for (int r = 0; r < 4; ++r)
            #pragma unroll
            for (int off = 1; off < 16; off <<= 1)
                psum[r] += __shfl_xor(psum[r], off);
        float linv[4];
        #pragma unroll
        for (int r = 0; r < 4; ++r) linv[r] = 1.f / psum[r];

        unsigned short* pw = Ps + w * (16 * PS_STRIDE);
        #pragma unroll
        for (int kt = 0; kt < 19; ++kt)
            #pragma unroll
            for (int r = 0; r < 4; ++r)
                pw[(quad * 4 + r) * PS_STRIDE + kt * 16 + l16] = f2bf(S[kt][r]);

        f32x4 o0, o1;
        #pragma unroll
        for (int r = 0; r < 4; ++r) { o0[r] = 0.f; o1[r] = 0.f; }
        #pragma unroll
        for (int ks = 0; ks < 10; ++ks) {
            bf16x8 ap = *(const bf16x8*)(pw + l16 * PS_STRIDE + ks * 32 + quad * 8);
            bf16x8 b0 = *(const bf16x8*)(Vs + l16 * PS_STRIDE + ks * 32 + quad * 8);
            bf16x8 b1 = *(const bf16x8*)(Vs + (16 + l16) * PS_STRIDE + ks * 32 + quad * 8);
            o0 = __builtin_amdgcn_mfma_f32_16x16x32_bf16(ap, b0, o0, 0, 0, 0);
            o1 = __builtin_amdgcn_mfma_f32_16x16x32_bf16(ap, b1, o1, 0, 0, 0);
        }
        #pragma unroll
        for (int r = 0; r < 4; ++r) {
            int q = qt * 16 + quad * 4 + r;
            if (q < LQ_) {
                size_t ob = ((size_t)b * LQ_ + q) * D_ + h * HD_;
                out[ob + l16]      = o0[r] * linv[r];
                out[ob + 16 + l16] = o1[r] * linv[r];
            }
        }
    }
}

// ---------------------------------------------------------------------------
// LayerNorm: out = LN(x + r) * g + b. One block per token.
// ---------------------------------------------------------------------------
__global__ __launch_bounds__(256)
void ln_kernel(const float* __restrict__ x, const float* __restrict__ r,
               const float* __restrict__ g, const float* __restrict__ bta,
               float* __restrict__ out) {
    const int tok = blockIdx.x;
    const int t = threadIdx.x;
    float v = x[(size_t)tok * D_ + t] + r[(size_t)tok * D_ + t];

    float s = v;
    #pragma unroll
    for (int i = 1; i < 64; i <<= 1) s += __shfl_xor(s, i);
    __shared__ float red1[4];
    if ((t & 63) == 0) red1[t >> 6] = s;
    __syncthreads();
    float mean = (red1[0] + red1[1] + red1[2] + red1[3]) * (1.0f / D_);

    float d = v - mean;
    float s2 = d * d;
    #pragma unroll
    for (int i = 1; i < 64; i <<= 1) s2 += __shfl_xor(s2, i);
    __shared__ float red2[4];
    if ((t & 63) == 0) red2[t >> 6] = s2;
    __syncthreads();
    float var = (red2[0] + red2[1] + red2[2] + red2[3]) * (1.0f / D_);

    out[(size_t)tok * D_ + t] = d * rsqrtf(var + 1e-5f) * g[t] + bta[t];
}

// ---------------------------------------------------------------------------
// Deformable sampling. 16 lanes per (b,q,h); lane = 2 channels (dword loads).
// ---------------------------------------------------------------------------
__global__ __launch_bounds__(256)
void deform_kernel(const unsigned short* __restrict__ value,
                   const float* __restrict__ off,
                   const float* __restrict__ awl,
                   const float* __restrict__ ref,
                   float* __restrict__ out) {
    const int lvl_hw[3]    = {80, 40, 20};
    const int lvl_start[3] = {0, 6400, 8000};
    const int gid = blockIdx.x * 16 + (threadIdx.x >> 4);   // (b,q,h)
    const int c2  = (threadIdx.x & 15) * 2;
    const int h   = gid & 7;
    const int bq  = gid >> 3;
    const int b   = bq / LQ_;

    float lg[12];
    const float* ap = awl + (size_t)bq * 96 + h * 12;
    float m = -1e30f;
    #pragma unroll
    for (int j = 0; j < 12; ++j) { lg[j] = ap[j]; m = fmaxf(m, lg[j]); }
    float s = 0.f;
    #pragma unroll
    for (int j = 0; j < 12; ++j) { lg[j] = __expf(lg[j] - m); s += lg[j]; }
    const float inv = 1.0f / s;

    const float* op = off + (size_t)bq * 192 + h * 24;
    const float* rp = ref + (size_t)bq * 6;

    float accx = 0.f, accy = 0.f;
    #pragma unroll
    for (int l = 0; l < NL_; ++l) {
        const int W = lvl_hw[l], H = lvl_hw[l];
        const float fw = (float)W, fh = (float)H;
        const float rx = rp[l * 2 + 0], ry = rp[l * 2 + 1];
        const unsigned short* vbase =
            value + ((size_t)b * LV_ + lvl_start[l]) * D_ + h * HD_ + c2;
        #pragma unroll
        for (int p = 0; p < NP_4; ++p) {
            float ox = op[(l * 4 + p) * 2 + 0], oy = op[(l * 4 + p) * 2 + 1];
            float x = (rx + ox / fw) * fw - 0.5f;
            float y = (ry + oy / fh) * fh - 0.5f;
            float x0f = floorf(x), y0f = floorf(y);
            float wx = x - x0f, wy = y - y0f;
            int x0 = (int)x0f, y0 = (int)y0f;
            float a = lg[l * 4 + p] * inv;
            const float cw[4] = {a * (1.f - wx) * (1.f - wy), a * wx * (1.f - wy),
                                 a * (1.f - wx) * wy,         a * wx * wy};
            const int cx[4] = {x0, x0 + 1, x0,     x0 + 1};
            const int cy[4] = {y0, y0,     y0 + 1, y0 + 1};
            #pragma unroll
            for (int cor = 0; cor < 4; ++cor) {
                int xi = cx[cor], yi = cy[cor];
                if (xi < 0 || xi >= W || yi < 0 || yi >= H) continue;
                unsigned v = *(const unsigned*)(vbase + (size_t)(yi * W + xi) * D_);
                accx += cw[cor] * bf2f((unsigned short)(v & 0xFFFFu));
                accy += cw[cor] * bf2f((unsigned short)(v >> 16));
            }
        }
    }
    float2 o2; o2.x = accx; o2.y = accy;
    *(float2*)(out + (size_t)bq * D_ + h * HD_ + c2) = o2;
}

// ---------------------------------------------------------------------------
// Launch
// ---------------------------------------------------------------------------
extern "C" void kernel_launch(void* const* d_in, const int* in_sizes, int n_in,
                              void* d_out, int out_size, void* d_ws, size_t ws_size,
                              hipStream_t stream) {
    const float* tgt   = (const float*)d_in[0];
    const float* refpt = (const float*)d_in[1];
    const float* mem   = (const float*)d_in[2];
    const float* qpos  = (const float*)d_in[3];
    const float* Wq = (const float*)d_in[6],  *bq = (const float*)d_in[7];
    const float* Wk = (const float*)d_in[8],  *bk = (const float*)d_in[9];
    const float* Wv = (const float*)d_in[10], *bv = (const float*)d_in[11];
    const float* Wo = (const float*)d_in[12], *bo = (const float*)d_in[13];
    const float* ln1_g = (const float*)d_in[14], *ln1_b = (const float*)d_in[15];
    const float* W_vproj = (const float*)d_in[16], *b_vproj = (const float*)d_in[17];
    const float* W_off  = (const float*)d_in[18], *b_off  = (const float*)d_in[19];
    const float* W_attn = (const float*)d_in[20], *b_attn = (const float*)d_in[21];
    const float* W_out  = (const float*)d_in[22], *b_out  = (const float*)d_in[23];
    const float* ln2_g = (const float*)d_in[24], *ln2_b = (const float*)d_in[25];
    const float* W1 = (const float*)d_in[26], *b1 = (const float*)d_in[27];
    const float* W2 = (const float*)d_in[28], *b2 = (const float*)d_in[29];
    const float* ln3_g = (const float*)d_in[30], *ln3_b = (const float*)d_in[31];
    float* out = (float*)d_out;

    // ---- workspace layout ----
    char* p = (char*)d_ws;
    const size_t TOKD = (size_t)NTOK * D_;
    float* buf_attn = (float*)p; p += TOKD * 4;
    float* buf_tmp  = (float*)p; p += TOKD * 4;
    float* buf_t1   = (float*)p; p += TOKD * 4;
    float* buf_t2   = (float*)p; p += TOKD * 4;
    unsigned short* buf_qh = (unsigned short*)p; p += TOKD * 2;
    unsigned short* buf_kh = (unsigned short*)p; p += TOKD * 2;
    unsigned short* buf_vh = (unsigned short*)p; p += TOKD * 2;
    float* buf_off  = (float*)p; p += (size_t)NTOK * 192 * 4;
    float* buf_awl  = (float*)p; p += (size_t)NTOK * 96 * 4;
    unsigned short* wt_q   = (unsigned short*)p; p += 65536 * 2;
    unsigned short* wt_k   = (unsigned short*)p; p += 65536 * 2;
    unsigned short* wt_v   = (unsigned short*)p; p += 65536 * 2;
    unsigned short* wt_o   = (unsigned short*)p; p += 65536 * 2;
    unsigned short* wt_vp  = (unsigned short*)p; p += 65536 * 2;
    unsigned short* wt_off = (unsigned short*)p; p += 49152 * 2;
    unsigned short* wt_awl = (unsigned short*)p; p += 24576 * 2;
    unsigned short* wt_out = (unsigned short*)p; p += 65536 * 2;
    unsigned short* wt_1   = (unsigned short*)p; p += (size_t)262144 * 2;
    unsigned short* wt_2   = (unsigned short*)p; p += (size_t)262144 * 2;
    unsigned short* buf_value = (unsigned short*)p;      // NVAL*256 bf16
    unsigned short* buf_ffnb  = (unsigned short*)p;      // aliases value (dead by FFN)

    // ---- weight transposes ----
    TrPack pk;
    pk.d[0] = {Wq,      wt_q,   256, 256};
    pk.d[1] = {Wk,      wt_k,   256, 256};
    pk.d[2] = {Wv,      wt_v,   256, 256};
    pk.d[3] = {Wo,      wt_o,   256, 256};
    pk.d[4] = {W_vproj, wt_vp,  256, 256};
    pk.d[5] = {W_off,   wt_off, 256, 192};
    pk.d[6] = {W_attn,  wt_awl, 256, 96};
    pk.d[7] = {W_out,   wt_out, 256, 256};
    pk.d[8] = {W1,      wt_1,   256, 1024};
    pk.d[9] = {W2,      wt_2,   1024, 256};
    tr_kernel<<<dim3(32, 32, 10), 256, 0, stream>>>(pk);

    // --- self attention ---
    gemm_wreg<32, 256, 4, 1, 2><<<dim3(1, NTOK / 32), 256, 0, stream>>>(
        tgt, qpos, wt_q, bq, buf_qh, NTOK, 256);
    gemm_wreg<32, 256, 4, 1, 2><<<dim3(1, NTOK / 32), 256, 0, stream>>>(
        tgt, qpos, wt_k, bk, buf_kh, NTOK, 256);
    gemm_wreg<32, 256, 4, 0, 2><<<dim3(1, NTOK / 32), 256, 0, stream>>>(
        tgt, nullptr, wt_v, bv, buf_vh, NTOK, 256);
    attn_mfma<<<BS_ * NH_ * 2, 256, 0, stream>>>(buf_qh, buf_kh, buf_vh, buf_attn);
    gemm_wreg<32, 256, 4, 0, 0><<<dim3(1, NTOK / 32), 256, 0, stream>>>(
        buf_attn, nullptr, wt_o, bo, buf_tmp, NTOK, 256);
    ln_kernel<<<NTOK, 256, 0, stream>>>(tgt, buf_tmp, ln1_g, ln1_b, buf_t1);

    // --- deformable cross attention ---
    gemm_wreg<64, 256, 4, 0, 2><<<dim3(1, NVAL / 64), 256, 0, stream>>>(
        mem, nullptr, wt_vp, b_vproj, buf_value, NVAL, 256);
    gemm_wreg<32, 256, 4, 1, 0><<<dim3(1, NTOK / 32), 256, 0, stream>>>(
        buf_t1, qpos, wt_off, b_off, buf_off, NTOK, 192);
    gemm_wreg<32, 256, 4, 1, 0><<<dim3(1, NTOK / 32), 256, 0, stream>>>(
        buf_t1, qpos, wt_awl, b_attn, buf_awl, NTOK, 96);
    deform_kernel<<<(BS_ * LQ_ * NH_) / 16, 256, 0, stream>>>(
        buf_value, buf_off, buf_awl, refpt, buf_attn);
    gemm_wreg<32, 256, 4, 0, 0><<<dim3(1, NTOK / 32), 256, 0, stream>>>(
        buf_attn, nullptr, wt_out, b_out, buf_tmp, NTOK, 256);
    ln_kernel<<<NTOK, 256, 0, stream>>>(buf_t1, buf_tmp, ln2_g, ln2_b, buf_t2);

    // --- FFN ---
    gemm_wreg<32, 256, 4, 0, 3><<<dim3(4, NTOK / 32), 256, 0, stream>>>(
        buf_t2, nullptr, wt_1, b1, buf_ffnb, NTOK, DFF_);
    gemm_wreg<16, 1024, 1, 2, 0><<<dim3(4, NTOK / 16), 256, 0, stream>>>(
        buf_ffnb, nullptr, wt_2, b2, buf_tmp, NTOK, 256);
    ln_kernel<<<NTOK, 256, 0, stream>>>(buf_t2, buf_tmp, ln3_g, ln3_b, out);
}

// Round 4
// 781.669 us; speedup vs baseline: 2.5245x; 1.0662x over previous
//
#include <hip/hip_runtime.h>
#include <hip/hip_bf16.h>

// Problem constants
#define D_      256
#define NH_     8
#define HD_     32
#define NL_     3
#define NP_4    4
#define BS_     32
#define LQ_     300
#define LV_     8400
#define DFF_    1024
#define NTOK    (BS_ * LQ_)        // 9600
#define NVAL    (BS_ * LV_)        // 268800

typedef __attribute__((ext_vector_type(8))) short bf16x8;
typedef __attribute__((ext_vector_type(4))) float f32x4;

__device__ inline unsigned short f2bf(float x) {
    union { float f; unsigned u; } v; v.f = x;
    unsigned r = v.u + 0x7FFFu + ((v.u >> 16) & 1u);
    return (unsigned short)(r >> 16);
}
__device__ inline float bf2f(unsigned short x) {
    union { unsigned u; float f; } v; v.u = ((unsigned)x) << 16;
    return v.f;
}

// ---------------------------------------------------------------------------
// Weight transpose+convert: Wt[n][k] = bf16(W[k][n]). 10 weights, one launch.
// ---------------------------------------------------------------------------
struct TrDesc { const float* W; unsigned short* Wt; int K; int N; };
struct TrPack { TrDesc d[10]; };

__global__ __launch_bounds__(256)
void tr_kernel(TrPack p) {
    TrDesc d = p.d[blockIdx.z];
    const int n0 = blockIdx.x * 32, k0 = blockIdx.y * 32;
    if (n0 >= d.N || k0 >= d.K) return;
    __shared__ float t[32][33];
    const int tx = threadIdx.x & 31, ty = threadIdx.x >> 5;
    #pragma unroll
    for (int i = 0; i < 4; ++i) {
        int k = k0 + ty + i * 8, n = n0 + tx;
        t[ty + i * 8][tx] = (k < d.K && n < d.N) ? d.W[(size_t)k * d.N + n] : 0.f;
    }
    __syncthreads();
    #pragma unroll
    for (int i = 0; i < 4; ++i) {
        int n = n0 + ty + i * 8, k = k0 + tx;
        if (n < d.N && k < d.K) d.Wt[(size_t)n * d.K + k] = f2bf(t[tx][ty + i * 8]);
    }
}

// ---------------------------------------------------------------------------
// One-shot whole-K LDS GEMM. C[M,N] = A @ W + bias, Wt = [N][K] bf16.
// Stage A-panel (ROWS x KC, bf16-converted) + B-panel (COLS x KC) to LDS,
// ONE barrier, then all MFMA k-steps barrier-free. NC = KK/KC chunks (>1 for
// FFN2). 4 waves in WR x WC grid. W stays in LDS (shared) -> low VGPR.
// AMODE: 0 = f32 A, 1 = f32 A + f32 A2 (fused add), 2 = bf16 A.
// CMODE: 0 = f32, 1 = f32 relu, 2 = bf16, 3 = bf16 relu.
// ---------------------------------------------------------------------------
template <int ROWS, int COLS, int KK, int KC, int WR, int WC, int AMODE, int CMODE>
__global__ __launch_bounds__(256, 1)
void gemm_os(const void* __restrict__ Ain, const float* __restrict__ A2,
             const unsigned short* __restrict__ Wt, const float* __restrict__ bias,
             void* __restrict__ Cout, int M, int N) {
    constexpr int LDK = KC + 8;              // stride 528/1040 B: uniform bank spread
    constexpr int NC = KK / KC;
    constexpr int KS = KC / 32;
    constexpr int WROWS = ROWS / WR, WCOLS = COLS / WC;
    constexpr int RT = WROWS / 16, TC = WCOLS / 16;
    __shared__ unsigned short Alds[ROWS * LDK];
    __shared__ unsigned short Blds[COLS * LDK];

    const int tid = threadIdx.x, lane = tid & 63, w = tid >> 6;
    const int quad = lane >> 4, l16 = lane & 15;
    const int wr = w / WC, wc = w % WC;
    const int rowBase = blockIdx.y * ROWS;
    const int colBase = blockIdx.x * COLS;

    f32x4 acc[RT][TC];
    #pragma unroll
    for (int rt = 0; rt < RT; ++rt)
        #pragma unroll
        for (int j = 0; j < TC; ++j)
            #pragma unroll
            for (int r = 0; r < 4; ++r) acc[rt][j][r] = 0.f;

    for (int ch = 0; ch < NC; ++ch) {
        if (NC > 1) __syncthreads();         // protect LDS before restage
        // ---- stage A chunk (coalesced: lane-consecutive 16B) ----
        {
            constexpr int CNT = ROWS * KC / 1024;     // float4 per thread (f32)
            if (AMODE == 2) {
                constexpr int CNT2 = ROWS * KC / 2048; // int4 per thread (bf16)
                #pragma unroll
                for (int i = 0; i < CNT2; ++i) {
                    int idx = i * 256 + tid;           // int4 index
                    int row = idx / (KC / 8), kofs = (idx % (KC / 8)) * 8;
                    int4 v = *(const int4*)((const unsigned short*)Ain +
                              (size_t)(rowBase + row) * KK + ch * KC + kofs);
                    *(int4*)&Alds[row * LDK + kofs] = v;
                }
            } else {
                #pragma unroll
                for (int i = 0; i < CNT; ++i) {
                    int idx = i * 256 + tid;           // float4 index
                    int row = idx / (KC / 4), kofs = (idx % (KC / 4)) * 4;
                    size_t g = (size_t)(rowBase + row) * KK + ch * KC + kofs;
                    float4 a = *(const float4*)((const float*)Ain + g);
                    if (AMODE == 1) {
                        float4 b = *(const float4*)(A2 + g);
                        a.x += b.x; a.y += b.y; a.z += b.z; a.w += b.w;
                    }
                    ushort4 s4;
                    s4.x = f2bf(a.x); s4.y = f2bf(a.y);
                    s4.z = f2bf(a.z); s4.w = f2bf(a.w);
                    *(ushort4*)&Alds[row * LDK + kofs] = s4;
                }
            }
        }
        // ---- stage B chunk ----
        {
            constexpr int CNT = COLS * KC / 2048;      // int4 per thread
            #pragma unroll
            for (int i = 0; i < CNT; ++i) {
                int idx = i * 256 + tid;
                int col = idx / (KC / 8), kofs = (idx % (KC / 8)) * 8;
                int4 v = *(const int4*)(Wt + (size_t)(colBase + col) * KK + ch * KC + kofs);
                *(int4*)&Blds[col * LDK + kofs] = v;
            }
        }
        __syncthreads();

        // ---- barrier-free MFMA over this chunk ----
        #pragma unroll
        for (int s = 0; s < KS; ++s) {
            bf16x8 af[RT], bf[TC];
            #pragma unroll
            for (int rt = 0; rt < RT; ++rt)
                af[rt] = *(const bf16x8*)&Alds[(wr * WROWS + rt * 16 + l16) * LDK + s * 32 + quad * 8];
            #pragma unroll
            for (int j = 0; j < TC; ++j)
                bf[j] = *(const bf16x8*)&Blds[(wc * WCOLS + j * 16 + l16) * LDK + s * 32 + quad * 8];
            #pragma unroll
            for (int rt = 0; rt < RT; ++rt)
                #pragma unroll
                for (int j = 0; j < TC; ++j)
                    acc[rt][j] = __builtin_amdgcn_mfma_f32_16x16x32_bf16(af[rt], bf[j], acc[rt][j], 0, 0, 0);
        }
    }

    // ---- epilogue ----
    #pragma unroll
    for (int rt = 0; rt < RT; ++rt) {
        #pragma unroll
        for (int j = 0; j < TC; ++j) {
            int col = colBase + wc * WCOLS + j * 16 + l16;
            float bb = bias[col];
            #pragma unroll
            for (int r = 0; r < 4; ++r) {
                int row = rowBase + wr * WROWS + rt * 16 + quad * 4 + r;
                float c = acc[rt][j][r] + bb;
                if (CMODE == 1 || CMODE == 3) c = fmaxf(c, 0.f);
                if (CMODE >= 2)
                    ((unsigned short*)Cout)[(size_t)row * N + col] = f2bf(c);
                else
                    ((float*)Cout)[(size_t)row * N + col] = c;
            }
        }
    }
}

// ---------------------------------------------------------------------------
// Flash-style MFMA self-attention. Block = (b, h, half); 512 blocks.
// ---------------------------------------------------------------------------
#define PS_STRIDE 344
__global__ __launch_bounds__(256)
void attn_mfma(const unsigned short* __restrict__ qh,
               const unsigned short* __restrict__ kh,
               const unsigned short* __restrict__ vh,
               float* __restrict__ out) {
    __shared__ unsigned short Ps[4 * 16 * PS_STRIDE];
    __shared__ unsigned short Vs[32 * PS_STRIDE];
    const int tid = threadIdx.x;
    const int bh = blockIdx.x >> 1, half_ = blockIdx.x & 1;
    const int b = bh >> 3, h = bh & 7;
    const int w = tid >> 6, lane = tid & 63;
    const int quad = lane >> 4, l16 = lane & 15;

    for (int i = tid; i < 4 * 16 * PS_STRIDE / 2; i += 256) ((unsigned*)Ps)[i] = 0u;

    const size_t hbase = ((size_t)b * LQ_) * D_ + h * HD_;
    for (int it = 0; it < 10; ++it) {
        int chunk = tid + 256 * it;
        int key = chunk >> 3, cc = (chunk & 7) * 4;
        ushort4 v = make_ushort4(0, 0, 0, 0);
        if (key < LQ_) v = *(const ushort4*)(vh + hbase + (size_t)key * D_ + cc);
        Vs[(cc + 0) * PS_STRIDE + key] = v.x;
        Vs[(cc + 1) * PS_STRIDE + key] = v.y;
        Vs[(cc + 2) * PS_STRIDE + key] = v.z;
        Vs[(cc + 3) * PS_STRIDE + key] = v.w;
    }
    __syncthreads();

    const unsigned short* qb = qh + hbase;
    const unsigned short* kb = kh + hbase;
    const float scale = 0.17677669529663687f;

    for (int qt = 10 * half_ + w; qt < 10 * half_ + 10 && qt < 19; qt += 4) {
        int rowq = qt * 16 + l16; if (rowq > LQ_ - 1) rowq = LQ_ - 1;
        bf16x8 aq = *(const bf16x8*)(qb + (size_t)rowq * D_ + quad * 8);

        f32x4 S[19];
        #pragma unroll
        for (int kt = 0; kt < 19; ++kt) {
            int rowk = kt * 16 + l16; if (rowk > LQ_ - 1) rowk = LQ_ - 1;
            bf16x8 bk = *(const bf16x8*)(kb + (size_t)rowk * D_ + quad * 8);
            f32x4 z; z[0] = z[1] = z[2] = z[3] = 0.f;
            S[kt] = __builtin_amdgcn_mfma_f32_16x16x32_bf16(aq, bk, z, 0, 0, 0);
        }
        float mrow[4] = {-1e30f, -1e30f, -1e30f, -1e30f};
        #pragma unroll
        for (int kt = 0; kt < 19; ++kt) {
            bool masked = (kt == 18) && (l16 >= 12);
            #pragma unroll
            for (int r = 0; r < 4; ++r) {
                float s = masked ? -1e30f : S[kt][r] * scale;
                S[kt][r] = s;
                mrow[r] = fmaxf(mrow[r], s);
            }
        }
        #pragma unroll
        for (int r = 0; r < 4; ++r)
            #pragma unroll
            for (int off = 1; off < 16; off <<= 1)
                mrow[r] = fmaxf(mrow[r], __shfl_xor(mrow[r], off));
        float psum[4] = {0.f, 0.f, 0.f, 0.f};
        #pragma unroll
        for (int kt = 0; kt < 19; ++kt)
            #pragma unroll
            for (int r = 0; r < 4; ++r) {
                float p = __expf(S[kt][r] - mrow[r]);
                S[kt][r] = p;
                psum[r] += p;
            }
        #pragma unroll
        for (int r = 0; r < 4; ++r)
            #pragma unroll
            for (int off = 1; off < 16; off <<= 1)
                psum[r] += __shfl_xor(psum[r], off);
        float linv[4];
        #pragma unroll
        for (int r = 0; r < 4; ++r) linv[r] = 1.f / psum[r];

        unsigned short* pw = Ps + w * (16 * PS_STRIDE);
        #pragma unroll
        for (int kt = 0; kt < 19; ++kt)
            #pragma unroll
            for (int r = 0; r < 4; ++r)
                pw[(quad * 4 + r) * PS_STRIDE + kt * 16 + l16] = f2bf(S[kt][r]);

        f32x4 o0, o1;
        #pragma unroll
        for (int r = 0; r < 4; ++r) { o0[r] = 0.f; o1[r] = 0.f; }
        #pragma unroll
        for (int ks = 0; ks < 10; ++ks) {
            bf16x8 ap = *(const bf16x8*)(pw + l16 * PS_STRIDE + ks * 32 + quad * 8);
            bf16x8 b0 = *(const bf16x8*)(Vs + l16 * PS_STRIDE + ks * 32 + quad * 8);
            bf16x8 b1 = *(const bf16x8*)(Vs + (16 + l16) * PS_STRIDE + ks * 32 + quad * 8);
            o0 = __builtin_amdgcn_mfma_f32_16x16x32_bf16(ap, b0, o0, 0, 0, 0);
            o1 = __builtin_amdgcn_mfma_f32_16x16x32_bf16(ap, b1, o1, 0, 0, 0);
        }
        #pragma unroll
        for (int r = 0; r < 4; ++r) {
            int q = qt * 16 + quad * 4 + r;
            if (q < LQ_) {
                size_t ob = ((size_t)b * LQ_ + q) * D_ + h * HD_;
                out[ob + l16]      = o0[r] * linv[r];
                out[ob + 16 + l16] = o1[r] * linv[r];
            }
        }
    }
}

// ---------------------------------------------------------------------------
// LayerNorm: out = LN(x + r) * g + b. One block per token.
// ---------------------------------------------------------------------------
__global__ __launch_bounds__(256)
void ln_kernel(const float* __restrict__ x, const float* __restrict__ r,
               const float* __restrict__ g, const float* __restrict__ bta,
               float* __restrict__ out) {
    const int tok = blockIdx.x;
    const int t = threadIdx.x;
    float v = x[(size_t)tok * D_ + t] + r[(size_t)tok * D_ + t];

    float s = v;
    #pragma unroll
    for (int i = 1; i < 64; i <<= 1) s += __shfl_xor(s, i);
    __shared__ float red1[4];
    if ((t & 63) == 0) red1[t >> 6] = s;
    __syncthreads();
    float mean = (red1[0] + red1[1] + red1[2] + red1[3]) * (1.0f / D_);

    float d = v - mean;
    float s2 = d * d;
    #pragma unroll
    for (int i = 1; i < 64; i <<= 1) s2 += __shfl_xor(s2, i);
    __shared__ float red2[4];
    if ((t & 63) == 0) red2[t >> 6] = s2;
    __syncthreads();
    float var = (red2[0] + red2[1] + red2[2] + red2[3]) * (1.0f / D_);

    out[(size_t)tok * D_ + t] = d * rsqrtf(var + 1e-5f) * g[t] + bta[t];
}

// ---------------------------------------------------------------------------
// Deformable sampling. 16 lanes per (b,q,h); lane = 2 channels (dword loads).
// ---------------------------------------------------------------------------
__global__ __launch_bounds__(256)
void deform_kernel(const unsigned short* __restrict__ value,
                   const float* __restrict__ off,
                   const float* __restrict__ awl,
                   const float* __restrict__ ref,
                   float* __restrict__ out) {
    const int lvl_hw[3]    = {80, 40, 20};
    const int lvl_start[3] = {0, 6400, 8000};
    const int gid = blockIdx.x * 16 + (threadIdx.x >> 4);   // (b,q,h)
    const int c2  = (threadIdx.x & 15) * 2;
    const int h   = gid & 7;
    const int bq  = gid >> 3;
    const int b   = bq / LQ_;

    float lg[12];
    const float* ap = awl + (size_t)bq * 96 + h * 12;
    float m = -1e30f;
    #pragma unroll
    for (int j = 0; j < 12; ++j) { lg[j] = ap[j]; m = fmaxf(m, lg[j]); }
    float s = 0.f;
    #pragma unroll
    for (int j = 0; j < 12; ++j) { lg[j] = __expf(lg[j] - m); s += lg[j]; }
    const float inv = 1.0f / s;

    const float* op = off + (size_t)bq * 192 + h * 24;
    const float* rp = ref + (size_t)bq * 6;

    float accx = 0.f, accy = 0.f;
    #pragma unroll
    for (int l = 0; l < NL_; ++l) {
        const int W = lvl_hw[l], H = lvl_hw[l];
        const float fw = (float)W, fh = (float)H;
        const float rx = rp[l * 2 + 0], ry = rp[l * 2 + 1];
        const unsigned short* vbase =
            value + ((size_t)b * LV_ + lvl_start[l]) * D_ + h * HD_ + c2;
        #pragma unroll
        for (int p = 0; p < NP_4; ++p) {
            float ox = op[(l * 4 + p) * 2 + 0], oy = op[(l * 4 + p) * 2 + 1];
            float x = (rx + ox / fw) * fw - 0.5f;
            float y = (ry + oy / fh) * fh - 0.5f;
            float x0f = floorf(x), y0f = floorf(y);
            float wx = x - x0f, wy = y - y0f;
            int x0 = (int)x0f, y0 = (int)y0f;
            float a = lg[l * 4 + p] * inv;
            const float cw[4] = {a * (1.f - wx) * (1.f - wy), a * wx * (1.f - wy),
                                 a * (1.f - wx) * wy,         a * wx * wy};
            const int cx[4] = {x0, x0 + 1, x0,     x0 + 1};
            const int cy[4] = {y0, y0,     y0 + 1, y0 + 1};
            #pragma unroll
            for (int cor = 0; cor < 4; ++cor) {
                int xi = cx[cor], yi = cy[cor];
                if (xi < 0 || xi >= W || yi < 0 || yi >= H) continue;
                unsigned v = *(const unsigned*)(vbase + (size_t)(yi * W + xi) * D_);
                accx += cw[cor] * bf2f((unsigned short)(v & 0xFFFFu));
                accy += cw[cor] * bf2f((unsigned short)(v >> 16));
            }
        }
    }
    float2 o2; o2.x = accx; o2.y = accy;
    *(float2*)(out + (size_t)bq * D_ + h * HD_ + c2) = o2;
}

// ---------------------------------------------------------------------------
// Launch
// ---------------------------------------------------------------------------
extern "C" void kernel_launch(void* const* d_in, const int* in_sizes, int n_in,
                              void* d_out, int out_size, void* d_ws, size_t ws_size,
                              hipStream_t stream) {
    const float* tgt   = (const float*)d_in[0];
    const float* refpt = (const float*)d_in[1];
    const float* mem   = (const float*)d_in[2];
    const float* qpos  = (const float*)d_in[3];
    const float* Wq = (const float*)d_in[6],  *bq = (const float*)d_in[7];
    const float* Wk = (const float*)d_in[8],  *bk = (const float*)d_in[9];
    const float* Wv = (const float*)d_in[10], *bv = (const float*)d_in[11];
    const float* Wo = (const float*)d_in[12], *bo = (const float*)d_in[13];
    const float* ln1_g = (const float*)d_in[14], *ln1_b = (const float*)d_in[15];
    const float* W_vproj = (const float*)d_in[16], *b_vproj = (const float*)d_in[17];
    const float* W_off  = (const float*)d_in[18], *b_off  = (const float*)d_in[19];
    const float* W_attn = (const float*)d_in[20], *b_attn = (const float*)d_in[21];
    const float* W_out  = (const float*)d_in[22], *b_out  = (const float*)d_in[23];
    const float* ln2_g = (const float*)d_in[24], *ln2_b = (const float*)d_in[25];
    const float* W1 = (const float*)d_in[26], *b1 = (const float*)d_in[27];
    const float* W2 = (const float*)d_in[28], *b2 = (const float*)d_in[29];
    const float* ln3_g = (const float*)d_in[30], *ln3_b = (const float*)d_in[31];
    float* out = (float*)d_out;

    // ---- workspace layout ----
    char* p = (char*)d_ws;
    const size_t TOKD = (size_t)NTOK * D_;
    float* buf_attn = (float*)p; p += TOKD * 4;
    float* buf_tmp  = (float*)p; p += TOKD * 4;
    float* buf_t1   = (float*)p; p += TOKD * 4;
    float* buf_t2   = (float*)p; p += TOKD * 4;
    unsigned short* buf_qh = (unsigned short*)p; p += TOKD * 2;
    unsigned short* buf_kh = (unsigned short*)p; p += TOKD * 2;
    unsigned short* buf_vh = (unsigned short*)p; p += TOKD * 2;
    float* buf_off  = (float*)p; p += (size_t)NTOK * 192 * 4;
    float* buf_awl  = (float*)p; p += (size_t)NTOK * 96 * 4;
    unsigned short* wt_q   = (unsigned short*)p; p += 65536 * 2;
    unsigned short* wt_k   = (unsigned short*)p; p += 65536 * 2;
    unsigned short* wt_v   = (unsigned short*)p; p += 65536 * 2;
    unsigned short* wt_o   = (unsigned short*)p; p += 65536 * 2;
    unsigned short* wt_vp  = (unsigned short*)p; p += 65536 * 2;
    unsigned short* wt_off = (unsigned short*)p; p += 49152 * 2;
    unsigned short* wt_awl = (unsigned short*)p; p += 24576 * 2;
    unsigned short* wt_out = (unsigned short*)p; p += 65536 * 2;
    unsigned short* wt_1   = (unsigned short*)p; p += (size_t)262144 * 2;
    unsigned short* wt_2   = (unsigned short*)p; p += (size_t)262144 * 2;
    unsigned short* buf_value = (unsigned short*)p;      // NVAL*256 bf16
    unsigned short* buf_ffnb  = (unsigned short*)p;      // aliases value (dead by FFN)

    // ---- weight transposes ----
    TrPack pk;
    pk.d[0] = {Wq,      wt_q,   256, 256};
    pk.d[1] = {Wk,      wt_k,   256, 256};
    pk.d[2] = {Wv,      wt_v,   256, 256};
    pk.d[3] = {Wo,      wt_o,   256, 256};
    pk.d[4] = {W_vproj, wt_vp,  256, 256};
    pk.d[5] = {W_off,   wt_off, 256, 192};
    pk.d[6] = {W_attn,  wt_awl, 256, 96};
    pk.d[7] = {W_out,   wt_out, 256, 256};
    pk.d[8] = {W1,      wt_1,   256, 1024};
    pk.d[9] = {W2,      wt_2,   1024, 256};
    tr_kernel<<<dim3(32, 32, 10), 256, 0, stream>>>(pk);

    // --- self attention ---
    gemm_os<32, 128, 256, 256, 1, 4, 1, 2><<<dim3(2, NTOK / 32), 256, 0, stream>>>(
        tgt, qpos, wt_q, bq, buf_qh, NTOK, 256);
    gemm_os<32, 128, 256, 256, 1, 4, 1, 2><<<dim3(2, NTOK / 32), 256, 0, stream>>>(
        tgt, qpos, wt_k, bk, buf_kh, NTOK, 256);
    gemm_os<32, 128, 256, 256, 1, 4, 0, 2><<<dim3(2, NTOK / 32), 256, 0, stream>>>(
        tgt, nullptr, wt_v, bv, buf_vh, NTOK, 256);
    attn_mfma<<<BS_ * NH_ * 2, 256, 0, stream>>>(buf_qh, buf_kh, buf_vh, buf_attn);
    gemm_os<32, 128, 256, 256, 1, 4, 0, 0><<<dim3(2, NTOK / 32), 256, 0, stream>>>(
        buf_attn, nullptr, wt_o, bo, buf_tmp, NTOK, 256);
    ln_kernel<<<NTOK, 256, 0, stream>>>(tgt, buf_tmp, ln1_g, ln1_b, buf_t1);

    // --- deformable cross attention ---
    gemm_os<128, 128, 256, 256, 2, 2, 0, 2><<<dim3(2, NVAL / 128), 256, 0, stream>>>(
        mem, nullptr, wt_vp, b_vproj, buf_value, NVAL, 256);
    gemm_os<32, 192, 256, 256, 1, 4, 1, 0><<<dim3(1, NTOK / 32), 256, 0, stream>>>(
        buf_t1, qpos, wt_off, b_off, buf_off, NTOK, 192);
    gemm_os<32, 96, 256, 256, 2, 2, 1, 0><<<dim3(1, NTOK / 32), 256, 0, stream>>>(
        buf_t1, qpos, wt_awl, b_attn, buf_awl, NTOK, 96);
    deform_kernel<<<(BS_ * LQ_ * NH_) / 16, 256, 0, stream>>>(
        buf_value, buf_off, buf_awl, refpt, buf_attn);
    gemm_os<32, 128, 256, 256, 1, 4, 0, 0><<<dim3(2, NTOK / 32), 256, 0, stream>>>(
        buf_attn, nullptr, wt_out, b_out, buf_tmp, NTOK, 256);
    ln_kernel<<<NTOK, 256, 0, stream>>>(buf_t1, buf_tmp, ln2_g, ln2_b, buf_t2);

    // --- FFN ---
    gemm_os<32, 128, 256, 256, 1, 4, 0, 3><<<dim3(8, NTOK / 32), 256, 0, stream>>>(
        buf_t2, nullptr, wt_1, b1, buf_ffnb, NTOK, DFF_);
    gemm_os<32, 64, 1024, 512, 1, 4, 2, 0><<<dim3(4, NTOK / 32), 256, 0, stream>>>(
        buf_ffnb, nullptr, wt_2, b2, buf_tmp, NTOK, 256);
    ln_kernel<<<NTOK, 256, 0, stream>>>(buf_t2, buf_tmp, ln3_g, ln3_b, out);
}